// Round 8
// baseline (113.549 us; speedup 1.0000x reference)
//
#include <hip/hip_runtime.h>

#define B 64
#define S 512
#define D 768
#define E 32
#define N_ENT (B * E)        // 2048
#define MPE 4
#define M (N_ENT * MPE)      // 8192
#define N_TYPES 6
#define P (B * E * (E - 1))  // 63488

#define D4 (D / 4)                     // 192 float4 slots per row
#define LSE_BLOCKS (N_ENT * D4 / 256)  // 1536 (exactly one f32x4/thread)
#define FEAT_SLOTS (P * 3 * D4)        // 36,569,088 float4 slots
#define TYPES_ELEMS (P * N_TYPES)      // 380,928
#define SWEEP_GRID 2048
#define NXCD 8
#define CHUNK (FEAT_SLOTS / NXCD)      // 4,571,136 slots = 7936 pairs = 8 docs
#define XSTRIDE ((SWEEP_GRID / NXCD) * 256)  // 65,536 threads per XCD

typedef float f32x4 __attribute__((ext_vector_type(4)));

__device__ __forceinline__ float lse4(float a, float b, float c, float d) {
    float mx = fmaxf(fmaxf(a, b), fmaxf(c, d));
    return logf(expf(a - mx) + expf(b - mx) + expf(c - mx) + expf(d - mx)) + mx;
}

// ---------------------------------------------------------------------------
// Kernel A — LSE only (unchanged from R6; prep measured ~3-5us).
// R3 lesson: LSE once per entity, never per pair. R5 lesson: no grid-wide
// barrier/fusion — device-scope spin storms L2 invalidates.
// ---------------------------------------------------------------------------
__global__ __launch_bounds__(256) void lse_kernel(
    const float* __restrict__ hidden,
    const int* __restrict__ mention_entity,
    const int* __restrict__ mention_pos,
    float* __restrict__ ent) {
    const unsigned idx = blockIdx.x * 256u + threadIdx.x;  // over N_ENT*D4
    const unsigned e = idx / D4;
    const unsigned d4 = idx - e * D4;
    const int doc = mention_entity[e * MPE] / E;
    const float* rowbase = hidden + (size_t)doc * S * D + (size_t)d4 * 4;

    f32x4 x[MPE];
#pragma unroll
    for (int m = 0; m < MPE; ++m) {
        const int pos = mention_pos[e * MPE + m] + 1;
        x[m] = *(const f32x4*)(rowbase + (size_t)pos * D);
    }
    f32x4 o;
    o.x = lse4(x[0].x, x[1].x, x[2].x, x[3].x);
    o.y = lse4(x[0].y, x[1].y, x[2].y, x[3].y);
    o.z = lse4(x[0].z, x[1].z, x[2].z, x[3].z);
    o.w = lse4(x[0].w, x[1].w, x[2].w, x[3].w);
    *(f32x4*)(ent + (size_t)e * D + (size_t)d4 * 4) = o;
}

// ---------------------------------------------------------------------------
// Kernel B — types prologue + the contiguous sweep, now XCD-partitioned:
// XCD x (= bid & 7, dispatch round-robin) owns slots [x*CHUNK, (x+1)*CHUNK)
// = exactly 8 whole docs. Each doc's ent rows (96 KB) are then resident in
// exactly ONE XCD's L2 instead of first-touched by all 8 (~50 MB of
// duplicate refills eliminated), and doc-boundary read stalls stagger
// across XCDs instead of hitting all at once. Per-XCD writes remain fully
// contiguous (each page written once — R2 lesson respected). Loop body,
// NT stores, index math all byte-identical to the 104us R1/R6 sweep.
// ---------------------------------------------------------------------------
__global__ __launch_bounds__(256) void sweep_kernel(
    const float* __restrict__ hidden,
    const int* __restrict__ pair_head,
    const int* __restrict__ pair_tail,
    const int* __restrict__ pair_doc,
    const int* __restrict__ ent_type,
    const float* __restrict__ ent,
    f32x4* __restrict__ out4,
    float* __restrict__ out_types) {
    const unsigned bid = blockIdx.x;
    const unsigned t = threadIdx.x;
    const unsigned gid = bid * 256u + t;

    // --- types prologue: <=1 element per thread (380,928 < 524,288) ---
    if (gid < (unsigned)TYPES_ELEMS) {
        const unsigned p = gid / N_TYPES;
        const int ty = (int)(gid - p * N_TYPES);
        const int th = ent_type[pair_head[p]];
        const int tt = ent_type[pair_tail[p]];
        out_types[gid] = (float)((ty == th) + (ty == tt));
    }

    // --- XCD-partitioned contiguous feature sweep ---
    const unsigned xcd = bid & (NXCD - 1u);      // dispatch round-robins XCDs
    const unsigned local = bid >> 3;             // 0..255 within this XCD
    const unsigned end = (xcd + 1u) * (unsigned)CHUNK;
    for (unsigned idx = xcd * (unsigned)CHUNK + local * 256u + t; idx < end;
         idx += (unsigned)XSTRIDE) {
        const unsigned p = idx / (3 * D4);          // magic mul
        const unsigned rem = idx - p * (3 * D4);
        const unsigned r = rem / D4;                // 0,1,2 (wave-uniform)
        const unsigned d4 = rem - r * D4;

        const f32x4* src;
        if (r == 0) {
            src = (const f32x4*)(hidden + (size_t)pair_doc[p] * (S * D));
        } else {
            const int q = (r == 1) ? pair_head[p] : pair_tail[p];
            src = (const f32x4*)(ent + (size_t)q * D);
        }
        __builtin_nontemporal_store(src[d4], &out4[idx]);
    }
}

extern "C" void kernel_launch(void* const* d_in, const int* in_sizes, int n_in,
                              void* d_out, int out_size, void* d_ws, size_t ws_size,
                              hipStream_t stream) {
    const float* hidden       = (const float*)d_in[0];
    const int* mention_entity = (const int*)d_in[1];
    const int* mention_pos    = (const int*)d_in[2];
    const int* pair_head      = (const int*)d_in[3];
    const int* pair_tail      = (const int*)d_in[4];
    const int* pair_doc       = (const int*)d_in[5];
    const int* ent_type       = (const int*)d_in[6];

    float* out       = (float*)d_out;
    f32x4* out4      = (f32x4*)out;              // P*3*D floats
    float* out_types = out + (size_t)P * 3 * D;  // P*N_TYPES floats
    float* ent       = (float*)d_ws;             // N_ENT*D floats = 6.3 MB

    lse_kernel<<<LSE_BLOCKS, 256, 0, stream>>>(
        hidden, mention_entity, mention_pos, ent);

    sweep_kernel<<<SWEEP_GRID, 256, 0, stream>>>(
        hidden, pair_head, pair_tail, pair_doc, ent_type, ent,
        out4, out_types);
}